// Round 3
// baseline (357.647 us; speedup 1.0000x reference)
//
#include <hip/hip_runtime.h>
#include <stdint.h>

// Q4_0 dequant-GEMM: y[t,o] = sum_k x[t,k] * s[o,k/32]*(q[o,k]-8) + bias[o]
// M=16 tokens, K=4096, N=11008. HBM-bound: 172 MiB int32 qweight stream,
// floor ~29 us at 6.3 TB/s.
//
// R7 = TIMING PROBE. R4/R5/R6 (convoy+atomics / write-once / 2-phase
// pipeline) all measure 253-257 us; qgemm never appears in rocprof top-5
// (<105 us) and the timed window is dominated by unconditional 688-MiB
// harness fills (105 us each). Ambiguity: window = 1 fill => T_qgemm~140us
// (structurally slow, worth attacking) vs 2 fills => T_qgemm~30us (BW floor,
// roofline). Probe: launch qgemm 3x (partial writes are idempotent ->
// correctness preserved). dur_us - 253 = 2*T_qgemm(warm). Decision:
// <=~35us/launch -> declare roofline next round; >=~50us -> optimize qgemm
// with known budget. Kernel bodies byte-identical to R6.

typedef __attribute__((ext_vector_type(8))) short bf16x8;  // 8 bf16 (4 VGPRs)
typedef __attribute__((ext_vector_type(4))) float f32x4;

#define OUT_F 11008
#define IN_F  4096
#define NB    128      // quant blocks along K
#define KSPLIT 4       // K-slices (one per block)
#define CHUNKS 4       // pipelined chunk-iterations per block
#define QB_IT 8        // qblocks staged per chunk (2 per wave)
#define NTILES (OUT_F / 16)      // 688 output tiles
#define NBLK (NTILES * KSPLIT)   // 2752 blocks
#define M_TOK 16
#define PROBE_REPS 3   // R7: timing probe (idempotent relaunches)

__global__ __launch_bounds__(256, 4)
void qgemm_kernel(const float* __restrict__ x,
                  const int* __restrict__ qw,
                  const float* __restrict__ scales,
                  const float* __restrict__ bias,
                  float* __restrict__ out,        // used only if part == nullptr
                  float* __restrict__ part) {     // [NBLK][256] partials
  // Double-buffered stage: 2 bufs x 8 qblock-slots x 2048 B. One slot = one
  // quant-block for all 64 lanes (part0 = lanes' first 16 B, part1 = second).
  __shared__ uint4 stage[2][QB_IT][128];   // 32 KB
  __shared__ float red[4][256];            // 4 KB

  const int bid  = blockIdx.x;
  const int kq   = bid & (KSPLIT - 1);
  const int ob   = (bid >> 2) << 4;        // 16 output features per tile
  const int tid  = threadIdx.x;
  const int wave = tid >> 6;
  const int lane = tid & 63;
  const int col  = lane & 15;              // output row (B) / token (A)
  const int kr   = lane >> 4;              // k sub-chunk 0..3

  const int kb_base = kq * (NB / KSPLIT);  // first of this block's 32 qblocks

  // Per-lane base addresses (row ob+col, 32 B sub-chunk kr).
  const char*  qbase = (const char*)qw + (size_t)(ob + col) * (IN_F * 4) + kr * 32;
  const float* xbase = x + col * IN_F + kr * 8;
  const float* sbase = scales + (ob + col) * NB;

  f32x4  xv[2][2][2];   // [parity][qblock][half] x registers (static-indexed)
  float2 scb[2];        // [parity] per-wave scale pair

  // Issue one chunk's staging: 4 x global_load_lds_dwordx4 per wave, no VGPR
  // landing. LDS dest is wave-uniform base + lane*16 (lane order == readback).
  auto STAGE = [&](int nb, int t) {
#pragma unroll
    for (int q = 0; q < 2; ++q) {
      const int slot = wave * 2 + q;
      const int kb   = kb_base + t * QB_IT + slot;
      const char* src = qbase + (size_t)kb * 128;
      __builtin_amdgcn_global_load_lds(
          (const __attribute__((address_space(1))) void*)src,
          (__attribute__((address_space(3))) void*)(&stage[nb][slot][0]),
          16, 0, 0);
      __builtin_amdgcn_global_load_lds(
          (const __attribute__((address_space(1))) void*)(src + 16),
          (__attribute__((address_space(3))) void*)(&stage[nb][slot][64]),
          16, 0, 0);
    }
  };
  // Prefetch x (L2-hot) + scales for chunk t into parity-p registers.
  auto PREF = [&](int p, int t) {
    const int kb0 = kb_base + t * QB_IT + wave * 2;
#pragma unroll
    for (int q = 0; q < 2; ++q) {
      const float* xp = xbase + (size_t)(kb0 + q) * 32;
      xv[p][q][0] = *(const f32x4*)xp;
      xv[p][q][1] = *(const f32x4*)(xp + 4);
    }
    scb[p] = *(const float2*)(sbase + kb0);
  };

  f32x4 acc = {0.f, 0.f, 0.f, 0.f};

  // Prologue: fill buffer 0, then drain (vmcnt(0) + barrier).
  STAGE(0, 0);
  PREF(0, 0);
  __syncthreads();

#pragma unroll
  for (int t = 0; t < CHUNKS; ++t) {
    const int nb = t & 1;
    if (t + 1 < CHUNKS) {      // issue next chunk: overlaps compute below
      STAGE(nb ^ 1, t + 1);
      PREF(nb ^ 1, t + 1);
    }
#pragma unroll
    for (int q = 0; q < 2; ++q) {
      const int slot = wave * 2 + q;
      // readback: this lane's 32 B of quants (2 x ds_read_b128, conflict-free)
      uint4 q0 = stage[nb][slot][lane];
      uint4 q1 = stage[nb][slot][64 + lane];
      float sc  = (q == 0) ? scb[nb].x : scb[nb].y;
      float m8s = -8.f * sc;
      union { uint32_t u[4]; bf16x8 v; } A, B;
      // pack x -> bf16 (round-half-up) via v_perm
      uint32_t a0 = __float_as_uint(xv[nb][q][0].x) + 0x8000u;
      uint32_t a1 = __float_as_uint(xv[nb][q][0].y) + 0x8000u;
      uint32_t a2 = __float_as_uint(xv[nb][q][0].z) + 0x8000u;
      uint32_t a3 = __float_as_uint(xv[nb][q][0].w) + 0x8000u;
      uint32_t a4 = __float_as_uint(xv[nb][q][1].x) + 0x8000u;
      uint32_t a5 = __float_as_uint(xv[nb][q][1].y) + 0x8000u;
      uint32_t a6 = __float_as_uint(xv[nb][q][1].z) + 0x8000u;
      uint32_t a7 = __float_as_uint(xv[nb][q][1].w) + 0x8000u;
      A.u[0] = __builtin_amdgcn_perm(a1, a0, 0x07060302u);
      A.u[1] = __builtin_amdgcn_perm(a3, a2, 0x07060302u);
      A.u[2] = __builtin_amdgcn_perm(a5, a4, 0x07060302u);
      A.u[3] = __builtin_amdgcn_perm(a7, a6, 0x07060302u);
      // dequant: w = s*q - 8s (exact in fp32), truncate-pack to bf16
      uint32_t w0 = __float_as_uint(fmaf((float)(int)q0.x, sc, m8s));
      uint32_t w1 = __float_as_uint(fmaf((float)(int)q0.y, sc, m8s));
      uint32_t w2 = __float_as_uint(fmaf((float)(int)q0.z, sc, m8s));
      uint32_t w3 = __float_as_uint(fmaf((float)(int)q0.w, sc, m8s));
      uint32_t w4 = __float_as_uint(fmaf((float)(int)q1.x, sc, m8s));
      uint32_t w5 = __float_as_uint(fmaf((float)(int)q1.y, sc, m8s));
      uint32_t w6 = __float_as_uint(fmaf((float)(int)q1.z, sc, m8s));
      uint32_t w7 = __float_as_uint(fmaf((float)(int)q1.w, sc, m8s));
      B.u[0] = __builtin_amdgcn_perm(w1, w0, 0x07060302u);
      B.u[1] = __builtin_amdgcn_perm(w3, w2, 0x07060302u);
      B.u[2] = __builtin_amdgcn_perm(w5, w4, 0x07060302u);
      B.u[3] = __builtin_amdgcn_perm(w7, w6, 0x07060302u);
      acc = __builtin_amdgcn_mfma_f32_16x16x32_bf16(A.v, B.v, acc, 0, 0, 0);
    }
    // vmcnt(0) drain + barrier: next chunk staged, this buffer free to reuse.
    __syncthreads();
  }

  // Cross-wave combine. C/D layout: lane holds D[row=kr*4+r][col].
#pragma unroll
  for (int r = 0; r < 4; ++r)
    red[wave][(kr * 4 + r) * 16 + col] = acc[r];
  __syncthreads();

  float v = red[0][tid] + red[1][tid] + red[2][tid] + red[3][tid];
  if (part) {
    // write-once partial: [tile*KSPLIT+kq][tid], fully coalesced
    part[(size_t)bid * 256 + tid] = v;
  } else {
    int t = tid >> 4;
    int o = ob + (tid & 15);
    if (kq == 0) v += bias[o];
    __hip_atomic_fetch_add(out + (size_t)t * OUT_F + o, v, __ATOMIC_RELAXED,
                           __HIP_MEMORY_SCOPE_AGENT);
  }
}

// Reduce 4 K-split partials + bias -> out. 176128 outputs, write-once.
// Partials are 2.8 MB written by the previous dispatch -> L2-resident reads.
__global__ __launch_bounds__(256)
void reduce_kernel(const float* __restrict__ part,
                   const float* __restrict__ bias,
                   float* __restrict__ out) {
  int idx = blockIdx.x * 256 + threadIdx.x;   // grid covers exactly 16*11008
  int t = idx / OUT_F;
  int o = idx - t * OUT_F;
  const float* p = part + (size_t)(o >> 4) * (KSPLIT * 256)
                 + ((t << 4) | (o & 15));
  float acc = bias[o];
#pragma unroll
  for (int kq = 0; kq < KSPLIT; ++kq)
    acc += p[kq * 256];
  out[idx] = acc;
}

// ---------------------------------------------------------------------------
extern "C" void kernel_launch(void* const* d_in, const int* in_sizes, int n_in,
                              void* d_out, int out_size, void* d_ws, size_t ws_size,
                              hipStream_t stream) {
  const float* x      = (const float*)d_in[0];
  const int*   qw     = (const int*)d_in[1];
  const float* scales = (const float*)d_in[2];
  const float* bias   = (const float*)d_in[3];
  float* out = (float*)d_out;

  const size_t need = (size_t)NBLK * 256 * sizeof(float);  // 2.8 MB
  if (d_ws != nullptr && ws_size >= need) {
    // Write-once path. R7 PROBE: launch qgemm PROBE_REPS times. Each launch
    // writes identical partial values (idempotent) -> correctness preserved.
    // dur_us - baseline(253) = (PROBE_REPS-1) * T_qgemm(L3-warm).
    float* p = (float*)d_ws;
    for (int rep = 0; rep < PROBE_REPS; ++rep)
      qgemm_kernel<<<NBLK, 256, 0, stream>>>(x, qw, scales, bias, nullptr, p);
    reduce_kernel<<<(M_TOK * OUT_F) / 256, 256, 0, stream>>>(p, bias, out);
  } else {
    // Fallback: zero-init + atomic K-split accumulate (single launch only --
    // atomics are NOT idempotent).
    hipMemsetAsync(out, 0, (size_t)M_TOK * OUT_F * sizeof(float), stream);
    qgemm_kernel<<<NBLK, 256, 0, stream>>>(x, qw, scales, bias, out, nullptr);
  }
}

// Round 5
// 254.962 us; speedup vs baseline: 1.4027x; 1.4027x over previous
//
#include <hip/hip_runtime.h>
#include <stdint.h>

// Q4_0 dequant-GEMM: y[t,o] = sum_k x[t,k] * s[o,k/32]*(q[o,k]-8) + bias[o]
// M=16 tokens, K=4096, N=11008. HBM floor ~29 us (172 MiB qweight @6.3TB/s).
//
// R7 probe: T_qgemm ~= 50 us L3-WARM => not memory-bound; limited by kernel
// structure. Harness-fixed window ~= 203 us. Headroom ~20 us.
//
// R8 theory: each wave reads back ONLY the LDS slots it staged itself
// (slot = wave*2+q) -- the per-chunk __syncthreads was never needed for
// sharing, only as a vmcnt drain. But it forces s_waitcnt vmcnt(0) +
// 4-wave lockstep 4x per block: the VMEM pipeline empties and restarts
// with a full HBM-latency bubble every chunk, all blocks convoying.
// R8 = T4 counted-vmcnt per-wave pipeline: NO barrier in the K-loop.
// Per iter: issue chunk t+1's 9 VMEM ops (4 global_load_lds + 4 x-loads +
// 1 scale-load), s_waitcnt vmcnt(9) (= chunk t's 9 done), sched_barrier(0)
// fences (rule #18), compute. vmcnt never hits 0 in steady state; waves
// free-run and stagger naturally. One __syncthreads remains before the
// cross-wave red[] combine. Dequant/pack/MFMA body byte-identical to R6.
// (R8 resubmit -- previous round failed on GPU acquisition, not the kernel.)

typedef __attribute__((ext_vector_type(8))) short bf16x8;  // 8 bf16 (4 VGPRs)
typedef __attribute__((ext_vector_type(4))) float f32x4;

#define OUT_F 11008
#define IN_F  4096
#define NB    128      // quant blocks along K
#define KSPLIT 4       // K-slices (one per block)
#define CHUNKS 4       // pipelined chunk-iterations per block
#define QB_IT 8        // qblocks staged per chunk (2 per wave)
#define NTILES (OUT_F / 16)      // 688 output tiles
#define NBLK (NTILES * KSPLIT)   // 2752 blocks
#define M_TOK 16

__global__ __launch_bounds__(256, 4)
void qgemm_kernel(const float* __restrict__ x,
                  const int* __restrict__ qw,
                  const float* __restrict__ scales,
                  const float* __restrict__ bias,
                  float* __restrict__ out,        // used only if part == nullptr
                  float* __restrict__ part) {     // [NBLK][256] partials
  // Double-buffered stage: 2 bufs x 8 qblock-slots x 2048 B. One slot = one
  // quant-block for all 64 lanes. Each wave stages AND reads only its own
  // two slots -> wave-private, no cross-wave sync needed in the K-loop.
  __shared__ uint4 stage[2][QB_IT][128];   // 32 KB
  __shared__ float red[4][256];            // 4 KB

  const int bid  = blockIdx.x;
  const int kq   = bid & (KSPLIT - 1);
  const int ob   = (bid >> 2) << 4;        // 16 output features per tile
  const int tid  = threadIdx.x;
  const int wave = tid >> 6;
  const int lane = tid & 63;
  const int col  = lane & 15;              // output row (B) / token (A)
  const int kr   = lane >> 4;              // k sub-chunk 0..3

  const int kb_base = kq * (NB / KSPLIT);  // first of this block's 32 qblocks

  // Per-lane base addresses (row ob+col, 32 B sub-chunk kr).
  const char*  qbase = (const char*)qw + (size_t)(ob + col) * (IN_F * 4) + kr * 32;
  const float* xbase = x + col * IN_F + kr * 8;
  const float* sbase = scales + (ob + col) * NB;

  f32x4  xv[2][2][2];   // [parity][qblock][half] registers (static-indexed)
  float2 scb[2];        // [parity] per-wave scale pair

  // Issue one chunk's staging: 4 x global_load_lds_dwordx4 per wave, no VGPR
  // landing. LDS dest is wave-uniform base + lane*16 (lane order == readback).
  auto STAGE = [&](int nb, int t) {
#pragma unroll
    for (int q = 0; q < 2; ++q) {
      const int slot = wave * 2 + q;
      const int kb   = kb_base + t * QB_IT + slot;
      const char* src = qbase + (size_t)kb * 128;
      __builtin_amdgcn_global_load_lds(
          (const __attribute__((address_space(1))) void*)src,
          (__attribute__((address_space(3))) void*)(&stage[nb][slot][0]),
          16, 0, 0);
      __builtin_amdgcn_global_load_lds(
          (const __attribute__((address_space(1))) void*)(src + 16),
          (__attribute__((address_space(3))) void*)(&stage[nb][slot][64]),
          16, 0, 0);
    }
  };
  // Prefetch x (L2-hot) + scales for chunk t into parity-p registers.
  // Exactly 5 VMEM ops: 4 x global_load_dwordx4 + 1 x global_load_dwordx2.
  auto PREF = [&](int p, int t) {
    const int kb0 = kb_base + t * QB_IT + wave * 2;
#pragma unroll
    for (int q = 0; q < 2; ++q) {
      const float* xp = xbase + (size_t)(kb0 + q) * 32;
      xv[p][q][0] = *(const f32x4*)xp;
      xv[p][q][1] = *(const f32x4*)(xp + 4);
    }
    scb[p] = *(const float2*)(sbase + kb0);
  };

  f32x4 acc = {0.f, 0.f, 0.f, 0.f};

  // Prologue: issue chunk 0 (9 VMEM ops), no drain -- iter 0's counted
  // wait covers it.
  STAGE(0, 0);
  PREF(0, 0);
  __builtin_amdgcn_sched_barrier(0);   // pin: chunk0 loads issue first

#pragma unroll
  for (int t = 0; t < CHUNKS; ++t) {
    const int nb = t & 1;
    if (t + 1 < CHUNKS) {      // issue next chunk: stays in flight past wait
      STAGE(nb ^ 1, t + 1);
      PREF(nb ^ 1, t + 1);
    }
    __builtin_amdgcn_sched_barrier(0); // pin issue order (vmcnt is in-order)
    // Counted wait: 9 newest (chunk t+1) may remain in flight; chunk t's
    // 4 global_load_lds + 5 reg-loads are complete. Last iter: drain.
    if (t + 1 < CHUNKS) {
      asm volatile("s_waitcnt vmcnt(9)" ::: "memory");
    } else {
      asm volatile("s_waitcnt vmcnt(0)" ::: "memory");
    }
    __builtin_amdgcn_sched_barrier(0); // rule #18: no ds_read above the wait
#pragma unroll
    for (int q = 0; q < 2; ++q) {
      const int slot = wave * 2 + q;
      // readback: this lane's 32 B of quants (2 x ds_read_b128, conflict-free)
      uint4 q0 = stage[nb][slot][lane];
      uint4 q1 = stage[nb][slot][64 + lane];
      float sc  = (q == 0) ? scb[nb].x : scb[nb].y;
      float m8s = -8.f * sc;
      union { uint32_t u[4]; bf16x8 v; } A, B;
      // pack x -> bf16 (round-half-up) via v_perm
      uint32_t a0 = __float_as_uint(xv[nb][q][0].x) + 0x8000u;
      uint32_t a1 = __float_as_uint(xv[nb][q][0].y) + 0x8000u;
      uint32_t a2 = __float_as_uint(xv[nb][q][0].z) + 0x8000u;
      uint32_t a3 = __float_as_uint(xv[nb][q][0].w) + 0x8000u;
      uint32_t a4 = __float_as_uint(xv[nb][q][1].x) + 0x8000u;
      uint32_t a5 = __float_as_uint(xv[nb][q][1].y) + 0x8000u;
      uint32_t a6 = __float_as_uint(xv[nb][q][1].z) + 0x8000u;
      uint32_t a7 = __float_as_uint(xv[nb][q][1].w) + 0x8000u;
      A.u[0] = __builtin_amdgcn_perm(a1, a0, 0x07060302u);
      A.u[1] = __builtin_amdgcn_perm(a3, a2, 0x07060302u);
      A.u[2] = __builtin_amdgcn_perm(a5, a4, 0x07060302u);
      A.u[3] = __builtin_amdgcn_perm(a7, a6, 0x07060302u);
      // dequant: w = s*q - 8s (exact in fp32), truncate-pack to bf16
      uint32_t w0 = __float_as_uint(fmaf((float)(int)q0.x, sc, m8s));
      uint32_t w1 = __float_as_uint(fmaf((float)(int)q0.y, sc, m8s));
      uint32_t w2 = __float_as_uint(fmaf((float)(int)q0.z, sc, m8s));
      uint32_t w3 = __float_as_uint(fmaf((float)(int)q0.w, sc, m8s));
      uint32_t w4 = __float_as_uint(fmaf((float)(int)q1.x, sc, m8s));
      uint32_t w5 = __float_as_uint(fmaf((float)(int)q1.y, sc, m8s));
      uint32_t w6 = __float_as_uint(fmaf((float)(int)q1.z, sc, m8s));
      uint32_t w7 = __float_as_uint(fmaf((float)(int)q1.w, sc, m8s));
      B.u[0] = __builtin_amdgcn_perm(w1, w0, 0x07060302u);
      B.u[1] = __builtin_amdgcn_perm(w3, w2, 0x07060302u);
      B.u[2] = __builtin_amdgcn_perm(w5, w4, 0x07060302u);
      B.u[3] = __builtin_amdgcn_perm(w7, w6, 0x07060302u);
      acc = __builtin_amdgcn_mfma_f32_16x16x32_bf16(A.v, B.v, acc, 0, 0, 0);
    }
    // no barrier: buffers are wave-private; next iter's counted wait
    // provides the only synchronization needed.
  }

  // Cross-wave combine. C/D layout: lane holds D[row=kr*4+r][col].
#pragma unroll
  for (int r = 0; r < 4; ++r)
    red[wave][(kr * 4 + r) * 16 + col] = acc[r];
  __syncthreads();   // the one real cross-wave sync

  float v = red[0][tid] + red[1][tid] + red[2][tid] + red[3][tid];
  if (part) {
    // write-once partial: [tile*KSPLIT+kq][tid], fully coalesced
    part[(size_t)bid * 256 + tid] = v;
  } else {
    int t = tid >> 4;
    int o = ob + (tid & 15);
    if (kq == 0) v += bias[o];
    __hip_atomic_fetch_add(out + (size_t)t * OUT_F + o, v, __ATOMIC_RELAXED,
                           __HIP_MEMORY_SCOPE_AGENT);
  }
}

// Reduce 4 K-split partials + bias -> out. 176128 outputs, write-once.
// Partials are 2.8 MB written by the previous dispatch -> L2-resident reads.
__global__ __launch_bounds__(256)
void reduce_kernel(const float* __restrict__ part,
                   const float* __restrict__ bias,
                   float* __restrict__ out) {
  int idx = blockIdx.x * 256 + threadIdx.x;   // grid covers exactly 16*11008
  int t = idx / OUT_F;
  int o = idx - t * OUT_F;
  const float* p = part + (size_t)(o >> 4) * (KSPLIT * 256)
                 + ((t << 4) | (o & 15));
  float acc = bias[o];
#pragma unroll
  for (int kq = 0; kq < KSPLIT; ++kq)
    acc += p[kq * 256];
  out[idx] = acc;
}

// ---------------------------------------------------------------------------
extern "C" void kernel_launch(void* const* d_in, const int* in_sizes, int n_in,
                              void* d_out, int out_size, void* d_ws, size_t ws_size,
                              hipStream_t stream) {
  const float* x      = (const float*)d_in[0];
  const int*   qw     = (const int*)d_in[1];
  const float* scales = (const float*)d_in[2];
  const float* bias   = (const float*)d_in[3];
  float* out = (float*)d_out;

  const size_t need = (size_t)NBLK * 256 * sizeof(float);  // 2.8 MB
  if (d_ws != nullptr && ws_size >= need) {
    // Write-once path: no memset, no atomics, no output RMW.
    float* p = (float*)d_ws;
    qgemm_kernel<<<NBLK, 256, 0, stream>>>(x, qw, scales, bias, nullptr, p);
    reduce_kernel<<<(M_TOK * OUT_F) / 256, 256, 0, stream>>>(p, bias, out);
  } else {
    // Fallback: zero-init + atomic K-split accumulate.
    hipMemsetAsync(out, 0, (size_t)M_TOK * OUT_F * sizeof(float), stream);
    qgemm_kernel<<<NBLK, 256, 0, stream>>>(x, qw, scales, bias, out, nullptr);
  }
}